// Round 17
// baseline (312.846 us; speedup 1.0000x reference)
//
#include <hip/hip_runtime.h>
#include <hip/hip_fp16.h>
#include <math.h>

#define NN 50000
#define NE 800000
#define GEPS 1e-15f
#define BN_EPS 1e-5f
#define NB 196      // (NN+255)/256
#define LOG2E 1.4426950408889634f
#define NODES_PER_XCD 6250   // NN/8 exactly -> bucket(dst) = dst/6250 in [0,8)
#define AGG_BLOCKS 2048
#define BUILD_BLOCKS 782     // ceil(NE/4/256)

typedef _Float16 f16x8 __attribute__((ext_vector_type(8)));
typedef float f32x4 __attribute__((ext_vector_type(4)));

__device__ __forceinline__ float2 h2f(unsigned int u) {
    __half2 h = *reinterpret_cast<const __half2*>(&u);
    return __half22float2(h);
}

// Fused init: zero deg (all blocks) + zero stats + compute gc (block 0). (R14: -5us)
__global__ void init_kernel(const float* __restrict__ sig1, const float* __restrict__ mu1,
                            const float* __restrict__ sig2, const float* __restrict__ mu2,
                            const float* __restrict__ sigs, const float* __restrict__ mus,
                            float* __restrict__ gc, int* __restrict__ deg,
                            float* __restrict__ stats) {
    int i = blockIdx.x * blockDim.x + threadIdx.x;
    if (i < NN) deg[i] = 0;
    if (blockIdx.x == 0) {
        int t = threadIdx.x;
        stats[t] = 0.f;   // 256 floats
        if (t < 11) {
            const float* sg; const float* mu;
            if (t < 5)       { sg = sig1 + t * 3;       mu = mu1 + t * 3; }
            else if (t < 10) { sg = sig2 + (t - 5) * 3; mu = mu2 + (t - 5) * 3; }
            else             { sg = sigs;               mu = mus; }
            float C = 0.f;
            for (int d = 0; d < 3; d++) {
                float sv = sg[d];
                float iv = -0.5f / (GEPS + sv * sv) * LOG2E;
                float m = mu[d];
                gc[t * 8 + d] = iv;
                gc[t * 8 + 3 + d] = -2.f * iv * m;
                C += iv * m * m;
            }
            gc[t * 8 + 6] = C;
            gc[t * 8 + 7] = 0.f;
        }
    }
}

// rank pass: rank[e] = seq-within-dst (COALESCED int4 write). deg counts for free.
__global__ void rank_kernel(const int* __restrict__ ei, int* __restrict__ deg,
                            int* __restrict__ rankv) {
    int t = blockIdx.x * blockDim.x + threadIdx.x;
    int e0 = t * 4;
    if (e0 >= NE) return;
    int4 dv = *(const int4*)(ei + NE + e0);
    int4 rv;
    rv.x = atomicAdd(&deg[dv.x], 1);
    rv.y = atomicAdd(&deg[dv.y], 1);
    rv.z = atomicAdd(&deg[dv.z], 1);
    rv.w = atomicAdd(&deg[dv.w], 1);
    *(int4*)(rankv + e0) = rv;
}

// ---- two-level scan (R15 lesson: single-block contiguous-per-thread scan was 93us) ----
__global__ void block_reduce_kernel(const int* __restrict__ deg, int* __restrict__ bsum) {
    __shared__ int sh[256];
    int t = threadIdx.x;
    int i = blockIdx.x * 256 + t;
    sh[t] = (i < NN) ? deg[i] : 0;
    __syncthreads();
    for (int off = 128; off > 0; off >>= 1) {
        if (t < off) sh[t] += sh[t + off];
        __syncthreads();
    }
    if (t == 0) bsum[blockIdx.x] = sh[0];
}

__global__ void scan_partials_kernel(int* __restrict__ bsum) {
    __shared__ int sh[256];
    int t = threadIdx.x;
    int v = (t < NB) ? bsum[t] : 0;
    sh[t] = v;
    __syncthreads();
    for (int off = 1; off < 256; off <<= 1) {
        int u = (t >= off) ? sh[t - off] : 0;
        __syncthreads();
        sh[t] += u;
        __syncthreads();
    }
    if (t < NB) bsum[t] = sh[t] - v;  // exclusive
}

__global__ void block_scan_kernel(const int* __restrict__ deg, const int* __restrict__ bsum,
                                  int* __restrict__ rowstart) {
    __shared__ int sh[256];
    int t = threadIdx.x;
    int i = blockIdx.x * 256 + t;
    int v = (i < NN) ? deg[i] : 0;
    sh[t] = v;
    __syncthreads();
    for (int off = 1; off < 256; off <<= 1) {
        int u = (t >= off) ? sh[t - off] : 0;
        __syncthreads();
        sh[t] += u;
        __syncthreads();
    }
    int excl = sh[t] - v + bsum[blockIdx.x];
    if (i < NN) rowstart[i] = excl;
}

// Heterogeneous launch: blocks [0,1024) = XCD-pinned perm scatter (R9, no atomics);
// blocks [1024,1536) = projR (independent work overlapped under the scatter). (R16: -3.5us)
__global__ void scatter_proj_kernel(const int* __restrict__ ei, const int* __restrict__ rankv,
                                    const int* __restrict__ rowstart, int* __restrict__ perm,
                                    const float* __restrict__ x, const float* __restrict__ root1,
                                    const float* __restrict__ b1, const float* __restrict__ roots,
                                    const float* __restrict__ bs, __half* __restrict__ xh,
                                    float* __restrict__ R1, float* __restrict__ Rs) {
    if (blockIdx.x < 1024) {
        const int g = blockIdx.x & 7;
        const int v = blockIdx.x >> 3;
        const int VB = 1024 >> 3;
        const int stride = VB * blockDim.x * 4;
        for (int e0 = (v * blockDim.x + threadIdx.x) * 4; e0 < NE; e0 += stride) {
            int4 dv = *(const int4*)(ei + NE + e0);
            int4 rv = *(const int4*)(rankv + e0);
            if (dv.x / NODES_PER_XCD == g) perm[rowstart[dv.x] + rv.x] = e0;
            if (dv.y / NODES_PER_XCD == g) perm[rowstart[dv.y] + rv.y] = e0 + 1;
            if (dv.z / NODES_PER_XCD == g) perm[rowstart[dv.z] + rv.z] = e0 + 2;
            if (dv.w / NODES_PER_XCD == g) perm[rowstart[dv.w] + rv.w] = e0 + 3;
        }
    } else {
        const int pb = blockIdx.x - 1024;
        const int t = threadIdx.x;
        const int col = t & 31;
        const int half_ = (t >> 5) & 1;
        const int rg = t >> 6;
        float w[32];
        const float* rootp = half_ ? roots : root1;
#pragma unroll
        for (int i = 0; i < 32; i++) w[i] = rootp[i * 32 + col];
        float b = half_ ? bs[col] : b1[col];
        float* Rp = half_ ? Rs : R1;
        __shared__ float hs[256];
        for (int n0 = pb * 8; n0 < NN; n0 += 512 * 8) {
            float v = x[(size_t)n0 * 32 + t];
            hs[t] = v;
            xh[(size_t)n0 * 32 + t] = __float2half(v);
            __syncthreads();
#pragma unroll
            for (int rr = 0; rr < 2; rr++) {
                int r = rg * 2 + rr;
                float acc = b;
#pragma unroll
                for (int i = 0; i < 32; i++) acc += w[i] * hs[r * 32 + i];
                Rp[(size_t)(n0 + r) * 32 + col] = acc;
            }
            __syncthreads();
        }
    }
}

// pos-major COALESCED record build — PASS A ONLY (slots 0..4 + skip 10). recB is built
// later, overlapped under agg<true> (it isn't needed until pass B). 4 edges/thread.
__global__ void buildA_kernel(const int* __restrict__ perm, const int* __restrict__ ei,
                              const float* __restrict__ ea, const float* __restrict__ gc,
                              int4* __restrict__ recA) {
    int t = blockIdx.x * blockDim.x + threadIdx.x;
    int p0 = t * 4;
    if (p0 >= NE) return;
    int4 pv = *(const int4*)(perm + p0);
    int es[4] = {pv.x, pv.y, pv.z, pv.w};

    int   srcs[4];
    float av[4][3];
#pragma unroll
    for (int k = 0; k < 4; k++) {
        int e = es[k];
        srcs[k] = ei[e];
        av[k][0] = ea[e * 3 + 0];
        av[k][1] = ea[e * 3 + 1];
        av[k][2] = ea[e * 3 + 2];
    }

    int4 qa[4];
#pragma unroll
    for (int k = 0; k < 4; k++) {
        float a0 = av[k][0], a1 = av[k][1], a2 = av[k][2];
        float s0 = a0 * a0, s1 = a1 * a1, s2 = a2 * a2;
        __half wv[6];
#pragma unroll
        for (int si = 0; si < 6; si++) {
            int s = (si < 5) ? si : 10;
            float ex = gc[s * 8 + 6];
            ex = fmaf(gc[s * 8 + 3], a0, ex);
            ex = fmaf(gc[s * 8 + 4], a1, ex);
            ex = fmaf(gc[s * 8 + 5], a2, ex);
            ex = fmaf(gc[s * 8 + 0], s0, ex);
            ex = fmaf(gc[s * 8 + 1], s1, ex);
            ex = fmaf(gc[s * 8 + 2], s2, ex);
            wv[si] = __float2half(exp2f(ex));
        }
        union UA { struct { int src; __half w[6]; } r; int4 q; } ua;
        ua.r.src = srcs[k];
        ua.r.w[0] = wv[0]; ua.r.w[1] = wv[1]; ua.r.w[2] = wv[2];
        ua.r.w[3] = wv[3]; ua.r.w[4] = wv[4]; ua.r.w[5] = wv[5];
        qa[k] = ua.q;
    }
#pragma unroll
    for (int k = 0; k < 4; k++) recA[p0 + k] = qa[k];
}

// h = elu(bn1(c1)) -> hh fp16; R2 = h@root2+b2. block=256, 8-row tiles.
__global__ void projB2_kernel(const float* __restrict__ c1, const float* __restrict__ stats,
                              const float* __restrict__ gam1, const float* __restrict__ bet1,
                              const float* __restrict__ root2, const float* __restrict__ b2,
                              __half* __restrict__ hh, float* __restrict__ R2) {
    const int t = threadIdx.x;
    const int col = t & 31;
    const int rg = t >> 5;
    __shared__ float sc[32], sf[32];
    if (t < 32) {
        const float invN = 1.0f / (float)NN;
        float m = stats[t] * invN;
        float v = stats[32 + t] * invN - m * m;
        float s = gam1[t] * rsqrtf(v + BN_EPS);
        sc[t] = s;
        sf[t] = bet1[t] - m * s;
    }
    float w[32];
#pragma unroll
    for (int i = 0; i < 32; i++) w[i] = root2[i * 32 + col];
    float b = b2[col];
    __shared__ float hs[256];
    __syncthreads();
    for (int n0 = blockIdx.x * 8; n0 < NN; n0 += gridDim.x * 8) {
        float v = c1[(size_t)n0 * 32 + t];
        float hv = sc[t & 31] * v + sf[t & 31];
        hv = hv > 0.f ? hv : (__expf(hv) - 1.f);
        hs[t] = hv;
        hh[(size_t)n0 * 32 + t] = __float2half(hv);
        __syncthreads();
        float acc = b;
#pragma unroll
        for (int i = 0; i < 32; i++) acc += w[i] * hs[rg * 32 + i];
        R2[(size_t)(n0 + rg) * 32 + col] = acc;
        __syncthreads();
    }
}

// agg edge-loop body shared by both variants (x2 unroll — R10: -12us; x4 regressed R13).
template <int NS, int SA>
__device__ __forceinline__ void agg_node_body(
        const int4* __restrict__ rec, const __half* __restrict__ X,
        __half* __restrict__ Aout, int n, int start, int d, int grp, int ch2) {
    float2 acc[NS];
#pragma unroll
    for (int s = 0; s < NS; s++) acc[s] = make_float2(0.f, 0.f);
    int i = grp;
    for (; i + 4 < d; i += 8) {
        int4 r0 = rec[(size_t)(start + i)];
        int4 r1 = rec[(size_t)(start + i + 4)];
        const __half2 xv0 = *(const __half2*)(X + (((size_t)r0.x) << 5) + 2 * ch2);
        const __half2 xv1 = *(const __half2*)(X + (((size_t)r1.x) << 5) + 2 * ch2);
        float2 xf0 = __half22float2(xv0);
        float2 xf1 = __half22float2(xv1);
        {
            float2 w01 = h2f((unsigned)r0.y);
            float2 w23 = h2f((unsigned)r0.z);
            float2 w45 = h2f((unsigned)r0.w);
            float wv[6] = {w01.x, w01.y, w23.x, w23.y, w45.x, w45.y};
#pragma unroll
            for (int s = 0; s < NS; s++) {
                acc[s].x = fmaf(wv[s], xf0.x, acc[s].x);
                acc[s].y = fmaf(wv[s], xf0.y, acc[s].y);
            }
        }
        {
            float2 w01 = h2f((unsigned)r1.y);
            float2 w23 = h2f((unsigned)r1.z);
            float2 w45 = h2f((unsigned)r1.w);
            float wv[6] = {w01.x, w01.y, w23.x, w23.y, w45.x, w45.y};
#pragma unroll
            for (int s = 0; s < NS; s++) {
                acc[s].x = fmaf(wv[s], xf1.x, acc[s].x);
                acc[s].y = fmaf(wv[s], xf1.y, acc[s].y);
            }
        }
    }
    if (i < d) {
        int4 r = rec[(size_t)(start + i)];
        const __half2 xv = *(const __half2*)(X + (((size_t)r.x) << 5) + 2 * ch2);
        float2 xf = __half22float2(xv);
        float2 w01 = h2f((unsigned)r.y);
        float2 w23 = h2f((unsigned)r.z);
        float2 w45 = h2f((unsigned)r.w);
        float wv[6] = {w01.x, w01.y, w23.x, w23.y, w45.x, w45.y};
#pragma unroll
        for (int s = 0; s < NS; s++) {
            acc[s].x = fmaf(wv[s], xf.x, acc[s].x);
            acc[s].y = fmaf(wv[s], xf.y, acc[s].y);
        }
    }
#pragma unroll
    for (int s = 0; s < NS; s++) {
        acc[s].x += __shfl_xor(acc[s].x, 16, 64);
        acc[s].x += __shfl_xor(acc[s].x, 32, 64);
        acc[s].y += __shfl_xor(acc[s].y, 16, 64);
        acc[s].y += __shfl_xor(acc[s].y, 32, 64);
    }
    if (grp == 0) {
        const float invd = 1.0f / fmaxf((float)d, 1.0f);
        __half* base = Aout + (size_t)n * SA + 2 * ch2;
#pragma unroll
        for (int s = 0; s < 5; s++) {
            __half2 hv = __floats2half2_rn(acc[s].x * invd, acc[s].y * invd);
            *(__half2*)(base + s * 32) = hv;
        }
        if (NS == 6) {
            __half2 hv = __floats2half2_rn(acc[5].x * invd, acc[5].y * invd);
            *(__half2*)(base + 160) = hv;
        }
    }
}

// Heterogeneous: blocks [0,2048) = agg<true> (recA, skip variant); blocks
// [2048,2048+782) = recB build (slots 5..9 — not needed until pass B, so it overlaps
// under the latency-bound aggregation instead of serializing before pass A).
__global__ void aggA_buildB_kernel(const int4* __restrict__ recA, const int* __restrict__ rowstart,
                                   const int* __restrict__ deg, const __half* __restrict__ X,
                                   __half* __restrict__ Aout, const int* __restrict__ perm,
                                   const int* __restrict__ ei, const float* __restrict__ ea,
                                   const float* __restrict__ gc, int4* __restrict__ recB) {
    if (blockIdx.x < AGG_BLOCKS) {
        const int tid = blockIdx.x * blockDim.x + threadIdx.x;
        const int lane = threadIdx.x & 63;
        const int grp = lane >> 4;
        const int ch2 = lane & 15;
        const int wavesTotal = (AGG_BLOCKS * 256) >> 6;
        const int wid = tid >> 6;
        for (int n = wid; n < NN; n += wavesTotal) {
            agg_node_body<6, 192>(recA, X, Aout, n, rowstart[n], deg[n], grp, ch2);
        }
    } else {
        int t = (blockIdx.x - AGG_BLOCKS) * blockDim.x + threadIdx.x;
        int p0 = t * 4;
        if (p0 >= NE) return;
        int4 pv = *(const int4*)(perm + p0);
        int es[4] = {pv.x, pv.y, pv.z, pv.w};
        int   srcs[4];
        float av[4][3];
#pragma unroll
        for (int k = 0; k < 4; k++) {
            int e = es[k];
            srcs[k] = ei[e];
            av[k][0] = ea[e * 3 + 0];
            av[k][1] = ea[e * 3 + 1];
            av[k][2] = ea[e * 3 + 2];
        }
        int4 qb[4];
#pragma unroll
        for (int k = 0; k < 4; k++) {
            float a0 = av[k][0], a1 = av[k][1], a2 = av[k][2];
            float s0 = a0 * a0, s1 = a1 * a1, s2 = a2 * a2;
            __half wv[5];
#pragma unroll
            for (int si = 0; si < 5; si++) {
                int s = 5 + si;
                float ex = gc[s * 8 + 6];
                ex = fmaf(gc[s * 8 + 3], a0, ex);
                ex = fmaf(gc[s * 8 + 4], a1, ex);
                ex = fmaf(gc[s * 8 + 5], a2, ex);
                ex = fmaf(gc[s * 8 + 0], s0, ex);
                ex = fmaf(gc[s * 8 + 1], s1, ex);
                ex = fmaf(gc[s * 8 + 2], s2, ex);
                wv[si] = __float2half(exp2f(ex));
            }
            union UB { struct { int src; __half w[5]; __half pad; } r; int4 q; } ub;
            ub.r.src = srcs[k];
            ub.r.w[0] = wv[0]; ub.r.w[1] = wv[1]; ub.r.w[2] = wv[2];
            ub.r.w[3] = wv[3]; ub.r.w[4] = wv[4]; ub.r.pad = __float2half(0.f);
            qb[k] = ub.q;
        }
#pragma unroll
        for (int k = 0; k < 4; k++) recB[p0 + k] = qb[k];
    }
}

// Plain agg for pass B (no skip).
__global__ void aggB_kernel(const int4* __restrict__ rec, const int* __restrict__ rowstart,
                            const int* __restrict__ deg, const __half* __restrict__ X,
                            __half* __restrict__ Aout) {
    const int tid = blockIdx.x * blockDim.x + threadIdx.x;
    const int lane = threadIdx.x & 63;
    const int grp = lane >> 4;
    const int ch2 = lane & 15;
    const int wavesTotal = (gridDim.x * blockDim.x) >> 6;
    const int wid = tid >> 6;
    for (int n = wid; n < NN; n += wavesTotal) {
        agg_node_body<5, 160>(rec, X, Aout, n, rowstart[n], deg[n], grp, ch2);
    }
}

// MFMA GEMM: C[n][c] = sum_kt A_kt[n][:] @ G_kt[:][c] + R[n][c]  (K=160, +skip K=32).
// Wave per 16-node tile, grid-strided. BN stats: per-wave shfl reduce -> per-block LDS
// reduce -> ONE global atomicAdd per block per element.
template <bool SKIP>
__global__ __launch_bounds__(256, 4) void gemm_kernel(
        const __half* __restrict__ Ah, const float* __restrict__ G,
        const float* __restrict__ Gs, const float* __restrict__ R,
        const float* __restrict__ Rs, float* __restrict__ C,
        float* __restrict__ Cs, float* __restrict__ stats) {
    constexpr int SA = SKIP ? 192 : 160;
    const int tid = blockIdx.x * blockDim.x + threadIdx.x;
    const int l = threadIdx.x & 63;
    const int r16 = l & 15;
    const int quad = l >> 4;
    const int wid = tid >> 6;
    const int nw = (gridDim.x * blockDim.x) >> 6;

    f16x8 bf[5][2];
#pragma unroll
    for (int kt = 0; kt < 5; kt++)
#pragma unroll
        for (int ct = 0; ct < 2; ct++)
#pragma unroll
            for (int e = 0; e < 8; e++) {
                int jj = quad * 8 + e;
                bf[kt][ct][e] = (_Float16)G[jj * 160 + kt * 32 + ct * 16 + r16];
            }
    f16x8 bs[2];
    if (SKIP) {
#pragma unroll
        for (int ct = 0; ct < 2; ct++)
#pragma unroll
            for (int e = 0; e < 8; e++) {
                int jj = quad * 8 + e;
                bs[ct][e] = (_Float16)Gs[jj * 32 + ct * 16 + r16];
            }
    }

    float s0 = 0.f, s1 = 0.f, q0 = 0.f, q1 = 0.f;
    float t0 = 0.f, t1 = 0.f, u0 = 0.f, u1 = 0.f;

    for (int tile = wid; tile < NN / 16; tile += nw) {
        const int n0 = tile * 16;
        const __half* arow = Ah + (size_t)(n0 + r16) * SA + quad * 8;
        f32x4 acc0 = {0.f, 0.f, 0.f, 0.f};
        f32x4 acc1 = {0.f, 0.f, 0.f, 0.f};
        f32x4 sa0 = {0.f, 0.f, 0.f, 0.f};
        f32x4 sa1 = {0.f, 0.f, 0.f, 0.f};
#pragma unroll
        for (int kt = 0; kt < 5; kt++) {
            f16x8 a = *(const f16x8*)(arow + kt * 32);
            acc0 = __builtin_amdgcn_mfma_f32_16x16x32_f16(a, bf[kt][0], acc0, 0, 0, 0);
            acc1 = __builtin_amdgcn_mfma_f32_16x16x32_f16(a, bf[kt][1], acc1, 0, 0, 0);
        }
        if (SKIP) {
            f16x8 a = *(const f16x8*)(arow + 160);
            sa0 = __builtin_amdgcn_mfma_f32_16x16x32_f16(a, bs[0], sa0, 0, 0, 0);
            sa1 = __builtin_amdgcn_mfma_f32_16x16x32_f16(a, bs[1], sa1, 0, 0, 0);
        }
#pragma unroll
        for (int r = 0; r < 4; r++) {
            const int nr = n0 + quad * 4 + r;
            const int b = nr * 32;
            {
                float v = acc0[r] + R[b + r16];
                C[b + r16] = v; s0 += v; q0 += v * v;
            }
            {
                float v = acc1[r] + R[b + 16 + r16];
                C[b + 16 + r16] = v; s1 += v; q1 += v * v;
            }
            if (SKIP) {
                float v = sa0[r] + Rs[b + r16];
                Cs[b + r16] = v; t0 += v; u0 += v * v;
                float w2 = sa1[r] + Rs[b + 16 + r16];
                Cs[b + 16 + r16] = w2; t1 += w2; u1 += w2 * w2;
            }
        }
    }
    s0 += __shfl_xor(s0, 16, 64); s0 += __shfl_xor(s0, 32, 64);
    s1 += __shfl_xor(s1, 16, 64); s1 += __shfl_xor(s1, 32, 64);
    q0 += __shfl_xor(q0, 16, 64); q0 += __shfl_xor(q0, 32, 64);
    q1 += __shfl_xor(q1, 16, 64); q1 += __shfl_xor(q1, 32, 64);
    if (SKIP) {
        t0 += __shfl_xor(t0, 16, 64); t0 += __shfl_xor(t0, 32, 64);
        t1 += __shfl_xor(t1, 16, 64); t1 += __shfl_xor(t1, 32, 64);
        u0 += __shfl_xor(u0, 16, 64); u0 += __shfl_xor(u0, 32, 64);
        u1 += __shfl_xor(u1, 16, 64); u1 += __shfl_xor(u1, 32, 64);
    }
    __shared__ float sred[128];
    const int t = threadIdx.x;
    if (t < 128) sred[t] = 0.f;
    __syncthreads();
    if (l < 16) {
        atomicAdd(&sred[l], s0);       atomicAdd(&sred[16 + l], s1);
        atomicAdd(&sred[32 + l], q0);  atomicAdd(&sred[48 + l], q1);
        if (SKIP) {
            atomicAdd(&sred[64 + l], t0);  atomicAdd(&sred[80 + l], t1);
            atomicAdd(&sred[96 + l], u0);  atomicAdd(&sred[112 + l], u1);
        }
    }
    __syncthreads();
    if (SKIP) { if (t < 128) atomicAdd(&stats[t], sred[t]); }
    else      { if (t < 64)  atomicAdd(&stats[t], sred[t]); }
}

// out = elu( bn2(c2) + bn_s(cs) ). stats: [0..63]=A conv, [64..127]=A skip, [128..191]=B conv.
__global__ void apply2_kernel(const float* __restrict__ c2, const float* __restrict__ cs,
                              const float* __restrict__ stats, const float* __restrict__ gam2,
                              const float* __restrict__ bet2, const float* __restrict__ gams,
                              const float* __restrict__ bets, float* __restrict__ out) {
    int idx = blockIdx.x * blockDim.x + threadIdx.x;
    if (idx >= NN * 32) return;
    int ch = idx & 31;
    const float invN = 1.0f / (float)NN;
    float m2 = stats[128 + ch] * invN;
    float v2 = stats[160 + ch] * invN - m2 * m2;
    float ms = stats[64 + ch] * invN;
    float vs = stats[96 + ch] * invN - ms * ms;
    float bn2 = gam2[ch] * (c2[idx] - m2) * rsqrtf(v2 + BN_EPS) + bet2[ch];
    float bns = gams[ch] * (cs[idx] - ms) * rsqrtf(vs + BN_EPS) + bets[ch];
    float o = bn2 + bns;
    out[idx] = o > 0.f ? o : (__expf(o) - 1.f);
}

extern "C" void kernel_launch(void* const* d_in, const int* in_sizes, int n_in,
                              void* d_out, int out_size, void* d_ws, size_t ws_size,
                              hipStream_t stream) {
    const float* x     = (const float*)d_in[0];
    const float* ea    = (const float*)d_in[1];
    const float* g1    = (const float*)d_in[2];
    const float* mu1   = (const float*)d_in[3];
    const float* sig1  = (const float*)d_in[4];
    const float* root1 = (const float*)d_in[5];
    const float* b1    = (const float*)d_in[6];
    const float* gam1  = (const float*)d_in[7];
    const float* bet1  = (const float*)d_in[8];
    const float* g2    = (const float*)d_in[9];
    const float* mu2   = (const float*)d_in[10];
    const float* sig2  = (const float*)d_in[11];
    const float* root2 = (const float*)d_in[12];
    const float* b2    = (const float*)d_in[13];
    const float* gam2  = (const float*)d_in[14];
    const float* bet2  = (const float*)d_in[15];
    const float* gs    = (const float*)d_in[16];
    const float* mus   = (const float*)d_in[17];
    const float* sigs  = (const float*)d_in[18];
    const float* roots = (const float*)d_in[19];
    const float* bs    = (const float*)d_in[20];
    const float* gams  = (const float*)d_in[21];
    const float* bets  = (const float*)d_in[22];
    const int*   ei    = (const int*)d_in[23];
    float* out = (float*)d_out;

    // ---- workspace layout ----
    char* w = (char*)d_ws;
    __half* xh  = (__half*)w;   w += (size_t)NN * 32 * 2;    // 3.2 MB
    __half* hh  = (__half*)w;   w += (size_t)NN * 32 * 2;    // 3.2 MB
    __half* Ah  = (__half*)w;   w += (size_t)NN * 192 * 2;   // 19.2 MB (pass B reuses as [n][160])
    float*  R1  = (float*)w;    w += (size_t)NN * 32 * 4;
    float*  Rs  = (float*)w;    w += (size_t)NN * 32 * 4;
    float*  R2  = (float*)w;    w += (size_t)NN * 32 * 4;
    float*  c1  = (float*)w;    w += (size_t)NN * 32 * 4;    // (reused as c2)
    float*  cs  = (float*)w;    w += (size_t)NN * 32 * 4;
    int4*   recA = (int4*)w;    w += (size_t)NE * 16;        // 12.8 MB
    int4*   recB = (int4*)w;    w += (size_t)NE * 16;        // 12.8 MB
    int*    perm = (int*)w;     w += (size_t)NE * 4;         // 3.2 MB
    int*    rankv = (int*)w;    w += (size_t)NE * 4;         // 3.2 MB
    int*    deg = (int*)w;      w += (size_t)NN * 4;
    int*    rowstart = (int*)w; w += (size_t)NN * 4;
    int*    bsum = (int*)w;     w += 256 * 4;
    float*  stats = (float*)w;  w += 256 * 4;
    float*  gc    = (float*)w;  w += 11 * 8 * 4;

    const int ilpBlocks   = (NE / 4 + 255) / 256;   // 4 edges/thread kernels
    const int applyBlocks = (NN * 32 + 255) / 256;

    // ---- init (fused: deg=0, stats=0, gc) ----
    init_kernel<<<NB, 256, 0, stream>>>(sig1, mu1, sig2, mu2, sigs, mus, gc, deg, stats);

    // ---- CSR build (once, shared by both aggs) ----
    rank_kernel<<<ilpBlocks, 256, 0, stream>>>(ei, deg, rankv);
    block_reduce_kernel<<<NB, 256, 0, stream>>>(deg, bsum);
    scan_partials_kernel<<<1, 256, 0, stream>>>(bsum);
    block_scan_kernel<<<NB, 256, 0, stream>>>(deg, bsum, rowstart);
    scatter_proj_kernel<<<1536, 256, 0, stream>>>(ei, rankv, rowstart, perm,
                                                  x, root1, b1, roots, bs, xh, R1, Rs);
    buildA_kernel<<<ilpBlocks, 256, 0, stream>>>(perm, ei, ea, gc, recA);

    // ---- pass A (recB build overlapped under agg<true>) ----
    aggA_buildB_kernel<<<AGG_BLOCKS + BUILD_BLOCKS, 256, 0, stream>>>(
        recA, rowstart, deg, xh, Ah, perm, ei, ea, gc, recB);
    gemm_kernel<true><<<512, 256, 0, stream>>>(Ah, g1, gs, R1, Rs, c1, cs, stats);

    // ---- pass B ----
    projB2_kernel<<<1024, 256, 0, stream>>>(c1, stats, gam1, bet1, root2, b2, hh, R2);
    aggB_kernel<<<2048, 256, 0, stream>>>(recB, rowstart, deg, hh, Ah);
    gemm_kernel<false><<<512, 256, 0, stream>>>(Ah, g2, nullptr, R2, nullptr, c1, nullptr,
                                                stats + 128);
    apply2_kernel<<<applyBlocks, 256, 0, stream>>>(c1, cs, stats, gam2, bet2, gams, bets, out);
}

// Round 18
// 293.759 us; speedup vs baseline: 1.0650x; 1.0650x over previous
//
#include <hip/hip_runtime.h>
#include <hip/hip_fp16.h>
#include <math.h>

#define NN 50000
#define NE 800000
#define GEPS 1e-15f
#define BN_EPS 1e-5f
#define NB 196      // (NN+255)/256
#define LOG2E 1.4426950408889634f
#define NODES_PER_XCD 6250   // NN/8 exactly -> bucket(dst) = dst/6250 in [0,8)

typedef _Float16 f16x8 __attribute__((ext_vector_type(8)));
typedef float f32x4 __attribute__((ext_vector_type(4)));

__device__ __forceinline__ float2 h2f(unsigned int u) {
    __half2 h = *reinterpret_cast<const __half2*>(&u);
    return __half22float2(h);
}

// Fused init: zero deg (all blocks) + zero stats + compute gc (block 0). (R14: -5us)
__global__ void init_kernel(const float* __restrict__ sig1, const float* __restrict__ mu1,
                            const float* __restrict__ sig2, const float* __restrict__ mu2,
                            const float* __restrict__ sigs, const float* __restrict__ mus,
                            float* __restrict__ gc, int* __restrict__ deg,
                            float* __restrict__ stats) {
    int i = blockIdx.x * blockDim.x + threadIdx.x;
    if (i < NN) deg[i] = 0;
    if (blockIdx.x == 0) {
        int t = threadIdx.x;
        stats[t] = 0.f;   // 256 floats
        if (t < 11) {
            const float* sg; const float* mu;
            if (t < 5)       { sg = sig1 + t * 3;       mu = mu1 + t * 3; }
            else if (t < 10) { sg = sig2 + (t - 5) * 3; mu = mu2 + (t - 5) * 3; }
            else             { sg = sigs;               mu = mus; }
            float C = 0.f;
            for (int d = 0; d < 3; d++) {
                float sv = sg[d];
                float iv = -0.5f / (GEPS + sv * sv) * LOG2E;
                float m = mu[d];
                gc[t * 8 + d] = iv;
                gc[t * 8 + 3 + d] = -2.f * iv * m;
                C += iv * m * m;
            }
            gc[t * 8 + 6] = C;
            gc[t * 8 + 7] = 0.f;
        }
    }
}

// rank pass: rank[e] = seq-within-dst (COALESCED int4 write). deg counts for free.
__global__ void rank_kernel(const int* __restrict__ ei, int* __restrict__ deg,
                            int* __restrict__ rankv) {
    int t = blockIdx.x * blockDim.x + threadIdx.x;
    int e0 = t * 4;
    if (e0 >= NE) return;
    int4 dv = *(const int4*)(ei + NE + e0);
    int4 rv;
    rv.x = atomicAdd(&deg[dv.x], 1);
    rv.y = atomicAdd(&deg[dv.y], 1);
    rv.z = atomicAdd(&deg[dv.z], 1);
    rv.w = atomicAdd(&deg[dv.w], 1);
    *(int4*)(rankv + e0) = rv;
}

// ---- two-level scan (R15 lesson: single-block contiguous-per-thread scan was 93us) ----
__global__ void block_reduce_kernel(const int* __restrict__ deg, int* __restrict__ bsum) {
    __shared__ int sh[256];
    int t = threadIdx.x;
    int i = blockIdx.x * 256 + t;
    sh[t] = (i < NN) ? deg[i] : 0;
    __syncthreads();
    for (int off = 128; off > 0; off >>= 1) {
        if (t < off) sh[t] += sh[t + off];
        __syncthreads();
    }
    if (t == 0) bsum[blockIdx.x] = sh[0];
}

__global__ void scan_partials_kernel(int* __restrict__ bsum) {
    __shared__ int sh[256];
    int t = threadIdx.x;
    int v = (t < NB) ? bsum[t] : 0;
    sh[t] = v;
    __syncthreads();
    for (int off = 1; off < 256; off <<= 1) {
        int u = (t >= off) ? sh[t - off] : 0;
        __syncthreads();
        sh[t] += u;
        __syncthreads();
    }
    if (t < NB) bsum[t] = sh[t] - v;  // exclusive
}

__global__ void block_scan_kernel(const int* __restrict__ deg, const int* __restrict__ bsum,
                                  int* __restrict__ rowstart) {
    __shared__ int sh[256];
    int t = threadIdx.x;
    int i = blockIdx.x * 256 + t;
    int v = (i < NN) ? deg[i] : 0;
    sh[t] = v;
    __syncthreads();
    for (int off = 1; off < 256; off <<= 1) {
        int u = (t >= off) ? sh[t - off] : 0;
        __syncthreads();
        sh[t] += u;
        __syncthreads();
    }
    int excl = sh[t] - v + bsum[blockIdx.x];
    if (i < NN) rowstart[i] = excl;
}

// Heterogeneous launch: blocks [0,1024) = XCD-pinned perm scatter (R9, no atomics);
// blocks [1024,1536) = projR (independent work overlapped under the scatter). (R16: -3.5us)
// R17 lesson: this overlap only works when total blocks fit the first dispatch wavefront
// (1536 < capacity); appending work past ~2048 blocks serializes behind the first role.
__global__ void scatter_proj_kernel(const int* __restrict__ ei, const int* __restrict__ rankv,
                                    const int* __restrict__ rowstart, int* __restrict__ perm,
                                    const float* __restrict__ x, const float* __restrict__ root1,
                                    const float* __restrict__ b1, const float* __restrict__ roots,
                                    const float* __restrict__ bs, __half* __restrict__ xh,
                                    float* __restrict__ R1, float* __restrict__ Rs) {
    if (blockIdx.x < 1024) {
        const int g = blockIdx.x & 7;
        const int v = blockIdx.x >> 3;
        const int VB = 1024 >> 3;
        const int stride = VB * blockDim.x * 4;
        for (int e0 = (v * blockDim.x + threadIdx.x) * 4; e0 < NE; e0 += stride) {
            int4 dv = *(const int4*)(ei + NE + e0);
            int4 rv = *(const int4*)(rankv + e0);
            if (dv.x / NODES_PER_XCD == g) perm[rowstart[dv.x] + rv.x] = e0;
            if (dv.y / NODES_PER_XCD == g) perm[rowstart[dv.y] + rv.y] = e0 + 1;
            if (dv.z / NODES_PER_XCD == g) perm[rowstart[dv.z] + rv.z] = e0 + 2;
            if (dv.w / NODES_PER_XCD == g) perm[rowstart[dv.w] + rv.w] = e0 + 3;
        }
    } else {
        const int pb = blockIdx.x - 1024;
        const int t = threadIdx.x;
        const int col = t & 31;
        const int half_ = (t >> 5) & 1;
        const int rg = t >> 6;
        float w[32];
        const float* rootp = half_ ? roots : root1;
#pragma unroll
        for (int i = 0; i < 32; i++) w[i] = rootp[i * 32 + col];
        float b = half_ ? bs[col] : b1[col];
        float* Rp = half_ ? Rs : R1;
        __shared__ float hs[256];
        for (int n0 = pb * 8; n0 < NN; n0 += 512 * 8) {
            float v = x[(size_t)n0 * 32 + t];
            hs[t] = v;
            xh[(size_t)n0 * 32 + t] = __float2half(v);
            __syncthreads();
#pragma unroll
            for (int rr = 0; rr < 2; rr++) {
                int r = rg * 2 + rr;
                float acc = b;
#pragma unroll
                for (int i = 0; i < 32; i++) acc += w[i] * hs[r * 32 + i];
                Rp[(size_t)(n0 + r) * 32 + col] = acc;
            }
            __syncthreads();
        }
    }
}

// pos-major COALESCED record build, 4 edges/thread (int4 perm load, 4 independent gather
// chains, full lane efficiency). recA 16B: {src, w_conv1[5], w_skip}; recB: {src, w_conv2[5]}.
__global__ void reorder_build(const int* __restrict__ perm, const int* __restrict__ ei,
                              const float* __restrict__ ea, const float* __restrict__ gc,
                              int4* __restrict__ recA, int4* __restrict__ recB) {
    int t = blockIdx.x * blockDim.x + threadIdx.x;
    int p0 = t * 4;
    if (p0 >= NE) return;
    int4 pv = *(const int4*)(perm + p0);
    int es[4] = {pv.x, pv.y, pv.z, pv.w};

    int   srcs[4];
    float av[4][3];
#pragma unroll
    for (int k = 0; k < 4; k++) {
        int e = es[k];
        srcs[k] = ei[e];
        av[k][0] = ea[e * 3 + 0];
        av[k][1] = ea[e * 3 + 1];
        av[k][2] = ea[e * 3 + 2];
    }

    int4 qa[4], qb[4];
#pragma unroll
    for (int k = 0; k < 4; k++) {
        float a0 = av[k][0], a1 = av[k][1], a2 = av[k][2];
        float s0 = a0 * a0, s1 = a1 * a1, s2 = a2 * a2;
        __half wv[11];
#pragma unroll
        for (int s = 0; s < 11; s++) {
            float ex = gc[s * 8 + 6];
            ex = fmaf(gc[s * 8 + 3], a0, ex);
            ex = fmaf(gc[s * 8 + 4], a1, ex);
            ex = fmaf(gc[s * 8 + 5], a2, ex);
            ex = fmaf(gc[s * 8 + 0], s0, ex);
            ex = fmaf(gc[s * 8 + 1], s1, ex);
            ex = fmaf(gc[s * 8 + 2], s2, ex);
            wv[s] = __float2half(exp2f(ex));
        }
        union UA { struct { int src; __half w[6]; } r; int4 q; } ua;
        ua.r.src = srcs[k];
        ua.r.w[0] = wv[0]; ua.r.w[1] = wv[1]; ua.r.w[2] = wv[2];
        ua.r.w[3] = wv[3]; ua.r.w[4] = wv[4]; ua.r.w[5] = wv[10];
        union UB { struct { int src; __half w[5]; __half pad; } r; int4 q; } ub;
        ub.r.src = srcs[k];
        ub.r.w[0] = wv[5]; ub.r.w[1] = wv[6]; ub.r.w[2] = wv[7];
        ub.r.w[3] = wv[8]; ub.r.w[4] = wv[9]; ub.r.pad = __float2half(0.f);
        qa[k] = ua.q;
        qb[k] = ub.q;
    }
#pragma unroll
    for (int k = 0; k < 4; k++) recA[p0 + k] = qa[k];
#pragma unroll
    for (int k = 0; k < 4; k++) recB[p0 + k] = qb[k];
}

// h = elu(bn1(c1)) -> hh fp16; R2 = h@root2+b2. block=256, 8-row tiles.
__global__ void projB2_kernel(const float* __restrict__ c1, const float* __restrict__ stats,
                              const float* __restrict__ gam1, const float* __restrict__ bet1,
                              const float* __restrict__ root2, const float* __restrict__ b2,
                              __half* __restrict__ hh, float* __restrict__ R2) {
    const int t = threadIdx.x;
    const int col = t & 31;
    const int rg = t >> 5;
    __shared__ float sc[32], sf[32];
    if (t < 32) {
        const float invN = 1.0f / (float)NN;
        float m = stats[t] * invN;
        float v = stats[32 + t] * invN - m * m;
        float s = gam1[t] * rsqrtf(v + BN_EPS);
        sc[t] = s;
        sf[t] = bet1[t] - m * s;
    }
    float w[32];
#pragma unroll
    for (int i = 0; i < 32; i++) w[i] = root2[i * 32 + col];
    float b = b2[col];
    __shared__ float hs[256];
    __syncthreads();
    for (int n0 = blockIdx.x * 8; n0 < NN; n0 += gridDim.x * 8) {
        float v = c1[(size_t)n0 * 32 + t];
        float hv = sc[t & 31] * v + sf[t & 31];
        hv = hv > 0.f ? hv : (__expf(hv) - 1.f);
        hs[t] = hv;
        hh[(size_t)n0 * 32 + t] = __float2half(hv);
        __syncthreads();
        float acc = b;
#pragma unroll
        for (int i = 0; i < 32; i++) acc += w[i] * hs[rg * 32 + i];
        R2[(size_t)(n0 + rg) * 32 + col] = acc;
        __syncthreads();
    }
}

// CSR gather-accumulate with PRECOMPUTED fp16 weights: A_s[dst][i] = (1/deg) * sum_e
// w_es * X[src_e][i]. One wave/node; 4 groups of 16 lanes (edge i%4==grp); lane owns a
// channel PAIR (half2 gather from 3.2MB L2-resident X). Edge loop unrolled x2 (R10: -12us
// e2e; R13's x4 regressed +16us — tail-loop overhead on Poisson(16) degrees — reverted).
template <bool SKIP>
__global__ void agg_kernel(const int4* __restrict__ rec, const int* __restrict__ rowstart,
                           const int* __restrict__ deg, const __half* __restrict__ X,
                           __half* __restrict__ Aout) {
    constexpr int NS = SKIP ? 6 : 5;
    constexpr int SA = SKIP ? 192 : 160;
    const int tid = blockIdx.x * blockDim.x + threadIdx.x;
    const int lane = threadIdx.x & 63;
    const int grp = lane >> 4;
    const int ch2 = lane & 15;
    const int wavesTotal = (gridDim.x * blockDim.x) >> 6;
    const int wid = tid >> 6;

    for (int n = wid; n < NN; n += wavesTotal) {
        const int start = rowstart[n];
        const int d = deg[n];
        float2 acc[NS];
#pragma unroll
        for (int s = 0; s < NS; s++) acc[s] = make_float2(0.f, 0.f);
        int i = grp;
        for (; i + 4 < d; i += 8) {
            int4 r0 = rec[(size_t)(start + i)];
            int4 r1 = rec[(size_t)(start + i + 4)];
            const __half2 xv0 = *(const __half2*)(X + (((size_t)r0.x) << 5) + 2 * ch2);
            const __half2 xv1 = *(const __half2*)(X + (((size_t)r1.x) << 5) + 2 * ch2);
            float2 xf0 = __half22float2(xv0);
            float2 xf1 = __half22float2(xv1);
            {
                float2 w01 = h2f((unsigned)r0.y);
                float2 w23 = h2f((unsigned)r0.z);
                float2 w45 = h2f((unsigned)r0.w);
                float wv[6] = {w01.x, w01.y, w23.x, w23.y, w45.x, w45.y};
#pragma unroll
                for (int s = 0; s < NS; s++) {
                    acc[s].x = fmaf(wv[s], xf0.x, acc[s].x);
                    acc[s].y = fmaf(wv[s], xf0.y, acc[s].y);
                }
            }
            {
                float2 w01 = h2f((unsigned)r1.y);
                float2 w23 = h2f((unsigned)r1.z);
                float2 w45 = h2f((unsigned)r1.w);
                float wv[6] = {w01.x, w01.y, w23.x, w23.y, w45.x, w45.y};
#pragma unroll
                for (int s = 0; s < NS; s++) {
                    acc[s].x = fmaf(wv[s], xf1.x, acc[s].x);
                    acc[s].y = fmaf(wv[s], xf1.y, acc[s].y);
                }
            }
        }
        if (i < d) {
            int4 r = rec[(size_t)(start + i)];
            const __half2 xv = *(const __half2*)(X + (((size_t)r.x) << 5) + 2 * ch2);
            float2 xf = __half22float2(xv);
            float2 w01 = h2f((unsigned)r.y);
            float2 w23 = h2f((unsigned)r.z);
            float2 w45 = h2f((unsigned)r.w);
            float wv[6] = {w01.x, w01.y, w23.x, w23.y, w45.x, w45.y};
#pragma unroll
            for (int s = 0; s < NS; s++) {
                acc[s].x = fmaf(wv[s], xf.x, acc[s].x);
                acc[s].y = fmaf(wv[s], xf.y, acc[s].y);
            }
        }
#pragma unroll
        for (int s = 0; s < NS; s++) {
            acc[s].x += __shfl_xor(acc[s].x, 16, 64);
            acc[s].x += __shfl_xor(acc[s].x, 32, 64);
            acc[s].y += __shfl_xor(acc[s].y, 16, 64);
            acc[s].y += __shfl_xor(acc[s].y, 32, 64);
        }
        if (grp == 0) {
            const float invd = 1.0f / fmaxf((float)d, 1.0f);
            __half* base = Aout + (size_t)n * SA + 2 * ch2;
#pragma unroll
            for (int s = 0; s < 5; s++) {
                __half2 hv = __floats2half2_rn(acc[s].x * invd, acc[s].y * invd);
                *(__half2*)(base + s * 32) = hv;
            }
            if (SKIP) {
                __half2 hv = __floats2half2_rn(acc[5].x * invd, acc[5].y * invd);
                *(__half2*)(base + 160) = hv;
            }
        }
    }
}

// MFMA GEMM: C[n][c] = sum_kt A_kt[n][:] @ G_kt[:][c] + R[n][c]  (K=160, +skip K=32).
// Wave per 16-node tile, grid-strided. BN stats: per-wave shfl reduce -> per-block LDS
// reduce -> ONE global atomicAdd per block per element.
template <bool SKIP>
__global__ __launch_bounds__(256, 4) void gemm_kernel(
        const __half* __restrict__ Ah, const float* __restrict__ G,
        const float* __restrict__ Gs, const float* __restrict__ R,
        const float* __restrict__ Rs, float* __restrict__ C,
        float* __restrict__ Cs, float* __restrict__ stats) {
    constexpr int SA = SKIP ? 192 : 160;
    const int tid = blockIdx.x * blockDim.x + threadIdx.x;
    const int l = threadIdx.x & 63;
    const int r16 = l & 15;
    const int quad = l >> 4;
    const int wid = tid >> 6;
    const int nw = (gridDim.x * blockDim.x) >> 6;

    f16x8 bf[5][2];
#pragma unroll
    for (int kt = 0; kt < 5; kt++)
#pragma unroll
        for (int ct = 0; ct < 2; ct++)
#pragma unroll
            for (int e = 0; e < 8; e++) {
                int jj = quad * 8 + e;
                bf[kt][ct][e] = (_Float16)G[jj * 160 + kt * 32 + ct * 16 + r16];
            }
    f16x8 bs[2];
    if (SKIP) {
#pragma unroll
        for (int ct = 0; ct < 2; ct++)
#pragma unroll
            for (int e = 0; e < 8; e++) {
                int jj = quad * 8 + e;
                bs[ct][e] = (_Float16)Gs[jj * 32 + ct * 16 + r16];
            }
    }

    float s0 = 0.f, s1 = 0.f, q0 = 0.f, q1 = 0.f;
    float t0 = 0.f, t1 = 0.f, u0 = 0.f, u1 = 0.f;

    for (int tile = wid; tile < NN / 16; tile += nw) {
        const int n0 = tile * 16;
        const __half* arow = Ah + (size_t)(n0 + r16) * SA + quad * 8;
        f32x4 acc0 = {0.f, 0.f, 0.f, 0.f};
        f32x4 acc1 = {0.f, 0.f, 0.f, 0.f};
        f32x4 sa0 = {0.f, 0.f, 0.f, 0.f};
        f32x4 sa1 = {0.f, 0.f, 0.f, 0.f};
#pragma unroll
        for (int kt = 0; kt < 5; kt++) {
            f16x8 a = *(const f16x8*)(arow + kt * 32);
            acc0 = __builtin_amdgcn_mfma_f32_16x16x32_f16(a, bf[kt][0], acc0, 0, 0, 0);
            acc1 = __builtin_amdgcn_mfma_f32_16x16x32_f16(a, bf[kt][1], acc1, 0, 0, 0);
        }
        if (SKIP) {
            f16x8 a = *(const f16x8*)(arow + 160);
            sa0 = __builtin_amdgcn_mfma_f32_16x16x32_f16(a, bs[0], sa0, 0, 0, 0);
            sa1 = __builtin_amdgcn_mfma_f32_16x16x32_f16(a, bs[1], sa1, 0, 0, 0);
        }
#pragma unroll
        for (int r = 0; r < 4; r++) {
            const int nr = n0 + quad * 4 + r;
            const int b = nr * 32;
            {
                float v = acc0[r] + R[b + r16];
                C[b + r16] = v; s0 += v; q0 += v * v;
            }
            {
                float v = acc1[r] + R[b + 16 + r16];
                C[b + 16 + r16] = v; s1 += v; q1 += v * v;
            }
            if (SKIP) {
                float v = sa0[r] + Rs[b + r16];
                Cs[b + r16] = v; t0 += v; u0 += v * v;
                float w2 = sa1[r] + Rs[b + 16 + r16];
                Cs[b + 16 + r16] = w2; t1 += w2; u1 += w2 * w2;
            }
        }
    }
    s0 += __shfl_xor(s0, 16, 64); s0 += __shfl_xor(s0, 32, 64);
    s1 += __shfl_xor(s1, 16, 64); s1 += __shfl_xor(s1, 32, 64);
    q0 += __shfl_xor(q0, 16, 64); q0 += __shfl_xor(q0, 32, 64);
    q1 += __shfl_xor(q1, 16, 64); q1 += __shfl_xor(q1, 32, 64);
    if (SKIP) {
        t0 += __shfl_xor(t0, 16, 64); t0 += __shfl_xor(t0, 32, 64);
        t1 += __shfl_xor(t1, 16, 64); t1 += __shfl_xor(t1, 32, 64);
        u0 += __shfl_xor(u0, 16, 64); u0 += __shfl_xor(u0, 32, 64);
        u1 += __shfl_xor(u1, 16, 64); u1 += __shfl_xor(u1, 32, 64);
    }
    __shared__ float sred[128];
    const int t = threadIdx.x;
    if (t < 128) sred[t] = 0.f;
    __syncthreads();
    if (l < 16) {
        atomicAdd(&sred[l], s0);       atomicAdd(&sred[16 + l], s1);
        atomicAdd(&sred[32 + l], q0);  atomicAdd(&sred[48 + l], q1);
        if (SKIP) {
            atomicAdd(&sred[64 + l], t0);  atomicAdd(&sred[80 + l], t1);
            atomicAdd(&sred[96 + l], u0);  atomicAdd(&sred[112 + l], u1);
        }
    }
    __syncthreads();
    if (SKIP) { if (t < 128) atomicAdd(&stats[t], sred[t]); }
    else      { if (t < 64)  atomicAdd(&stats[t], sred[t]); }
}

// out = elu( bn2(c2) + bn_s(cs) ). stats: [0..63]=A conv, [64..127]=A skip, [128..191]=B conv.
__global__ void apply2_kernel(const float* __restrict__ c2, const float* __restrict__ cs,
                              const float* __restrict__ stats, const float* __restrict__ gam2,
                              const float* __restrict__ bet2, const float* __restrict__ gams,
                              const float* __restrict__ bets, float* __restrict__ out) {
    int idx = blockIdx.x * blockDim.x + threadIdx.x;
    if (idx >= NN * 32) return;
    int ch = idx & 31;
    const float invN = 1.0f / (float)NN;
    float m2 = stats[128 + ch] * invN;
    float v2 = stats[160 + ch] * invN - m2 * m2;
    float ms = stats[64 + ch] * invN;
    float vs = stats[96 + ch] * invN - ms * ms;
    float bn2 = gam2[ch] * (c2[idx] - m2) * rsqrtf(v2 + BN_EPS) + bet2[ch];
    float bns = gams[ch] * (cs[idx] - ms) * rsqrtf(vs + BN_EPS) + bets[ch];
    float o = bn2 + bns;
    out[idx] = o > 0.f ? o : (__expf(o) - 1.f);
}

extern "C" void kernel_launch(void* const* d_in, const int* in_sizes, int n_in,
                              void* d_out, int out_size, void* d_ws, size_t ws_size,
                              hipStream_t stream) {
    const float* x     = (const float*)d_in[0];
    const float* ea    = (const float*)d_in[1];
    const float* g1    = (const float*)d_in[2];
    const float* mu1   = (const float*)d_in[3];
    const float* sig1  = (const float*)d_in[4];
    const float* root1 = (const float*)d_in[5];
    const float* b1    = (const float*)d_in[6];
    const float* gam1  = (const float*)d_in[7];
    const float* bet1  = (const float*)d_in[8];
    const float* g2    = (const float*)d_in[9];
    const float* mu2   = (const float*)d_in[10];
    const float* sig2  = (const float*)d_in[11];
    const float* root2 = (const float*)d_in[12];
    const float* b2    = (const float*)d_in[13];
    const float* gam2  = (const float*)d_in[14];
    const float* bet2  = (const float*)d_in[15];
    const float* gs    = (const float*)d_in[16];
    const float* mus   = (const float*)d_in[17];
    const float* sigs  = (const float*)d_in[18];
    const float* roots = (const float*)d_in[19];
    const float* bs    = (const float*)d_in[20];
    const float* gams  = (const float*)d_in[21];
    const float* bets  = (const float*)d_in[22];
    const int*   ei    = (const int*)d_in[23];
    float* out = (float*)d_out;

    // ---- workspace layout ----
    char* w = (char*)d_ws;
    __half* xh  = (__half*)w;   w += (size_t)NN * 32 * 2;    // 3.2 MB
    __half* hh  = (__half*)w;   w += (size_t)NN * 32 * 2;    // 3.2 MB
    __half* Ah  = (__half*)w;   w += (size_t)NN * 192 * 2;   // 19.2 MB (pass B reuses as [n][160])
    float*  R1  = (float*)w;    w += (size_t)NN * 32 * 4;
    float*  Rs  = (float*)w;    w += (size_t)NN * 32 * 4;
    float*  R2  = (float*)w;    w += (size_t)NN * 32 * 4;
    float*  c1  = (float*)w;    w += (size_t)NN * 32 * 4;    // (reused as c2)
    float*  cs  = (float*)w;    w += (size_t)NN * 32 * 4;
    int4*   recA = (int4*)w;    w += (size_t)NE * 16;        // 12.8 MB
    int4*   recB = (int4*)w;    w += (size_t)NE * 16;        // 12.8 MB
    int*    perm = (int*)w;     w += (size_t)NE * 4;         // 3.2 MB
    int*    rankv = (int*)w;    w += (size_t)NE * 4;         // 3.2 MB
    int*    deg = (int*)w;      w += (size_t)NN * 4;
    int*    rowstart = (int*)w; w += (size_t)NN * 4;
    int*    bsum = (int*)w;     w += 256 * 4;
    float*  stats = (float*)w;  w += 256 * 4;
    float*  gc    = (float*)w;  w += 11 * 8 * 4;

    const int ilpBlocks   = (NE / 4 + 255) / 256;   // 4 edges/thread kernels
    const int applyBlocks = (NN * 32 + 255) / 256;

    // ---- init (fused: deg=0, stats=0, gc) ----
    init_kernel<<<NB, 256, 0, stream>>>(sig1, mu1, sig2, mu2, sigs, mus, gc, deg, stats);

    // ---- CSR build (once, shared by both aggs) ----
    rank_kernel<<<ilpBlocks, 256, 0, stream>>>(ei, deg, rankv);
    block_reduce_kernel<<<NB, 256, 0, stream>>>(deg, bsum);
    scan_partials_kernel<<<1, 256, 0, stream>>>(bsum);
    block_scan_kernel<<<NB, 256, 0, stream>>>(deg, bsum, rowstart);
    scatter_proj_kernel<<<1536, 256, 0, stream>>>(ei, rankv, rowstart, perm,
                                                  x, root1, b1, roots, bs, xh, R1, Rs);
    reorder_build<<<ilpBlocks, 256, 0, stream>>>(perm, ei, ea, gc, recA, recB);

    // ---- pass A ----
    agg_kernel<true><<<2048, 256, 0, stream>>>(recA, rowstart, deg, xh, Ah);
    gemm_kernel<true><<<512, 256, 0, stream>>>(Ah, g1, gs, R1, Rs, c1, cs, stats);

    // ---- pass B ----
    projB2_kernel<<<1024, 256, 0, stream>>>(c1, stats, gam1, bet1, root2, b2, hh, R2);
    agg_kernel<false><<<2048, 256, 0, stream>>>(recB, rowstart, deg, hh, Ah);
    gemm_kernel<false><<<512, 256, 0, stream>>>(Ah, g2, nullptr, R2, nullptr, c1, nullptr,
                                                stats + 128);
    apply2_kernel<<<applyBlocks, 256, 0, stream>>>(c1, cs, stats, gam2, bet2, gams, bets, out);
}